// Round 4
// baseline (299.659 us; speedup 1.0000x reference)
//
#include <hip/hip_runtime.h>
#include <hip/hip_bf16.h>
#include <cstdint>

// Problem constants: b=2, dim=192, heads=6, ch=32, h=w=48, n=2304
#define NSP   2304
#define NT    144            // 2304/16 n-tiles
#define ATTN_ELEMS 63700992  // 2*6*2304*2304
#define EPAD  2312           // LDS row stride (bf16 elems) to break bank alias
#define ATTN_LDS (16*EPAD*2 + 64*4 + 16*4)

typedef __attribute__((ext_vector_type(8))) __bf16 bf16x8;   // MFMA A/B frag (4 VGPRs)
typedef __attribute__((ext_vector_type(4))) float  float4v;  // MFMA C/D frag + vec store

// round-to-nearest-even float -> bf16 bits
__device__ __forceinline__ unsigned short f2bf(float f) {
  union { float f; unsigned int u; } v; v.f = f;
  unsigned int u = v.u;
  unsigned int r = u + 0x7FFFu + ((u >> 16) & 1u);
  return (unsigned short)(r >> 16);
}

// ---------------------------------------------------------------------------
// Kernel 1: pack weights (M=576 = [wq;wk;wv]) and x into MFMA fragment layouts
//   A-frag layout: elem jj of lane -> [m = lane&15][k = (lane>>4)*8 + jj]
//   B-frag layout: elem jj of lane -> [k = (lane>>4)*8 + jj][n = lane&15]
// Also zeroes the 768-float sumsq accumulator (blocks 0..2).
// ---------------------------------------------------------------------------
__global__ __launch_bounds__(256) void prep_pack(
    const float* __restrict__ wq, const float* __restrict__ wk,
    const float* __restrict__ wv, const float* __restrict__ x,
    unsigned short* __restrict__ Wp, unsigned short* __restrict__ Xp,
    float* __restrict__ sumsq)
{
  if (blockIdx.x < 3) {
    int z = blockIdx.x * 256 + threadIdx.x;
    if (z < 768) sumsq[z] = 0.0f;
  }
  int t = blockIdx.x * 256 + threadIdx.x;      // 486*256 = 124416 = 1944 groups
  int lane = t & 63;
  int g = t >> 6;
  int quad = lane >> 4, col = lane & 15;
  union { int4 v; unsigned short u[8]; } o;
  if (g < 216) {                               // W: 36*6 groups
    int mt = g / 6, kc = g % 6;
    int oo = mt * 16 + col;
    int c0 = kc * 32 + quad * 8;
    const float* w = (oo < 192) ? (wq + (size_t)oo * 192)
                   : (oo < 384) ? (wk + (size_t)(oo - 192) * 192)
                                : (wv + (size_t)(oo - 384) * 192);
#pragma unroll
    for (int jj = 0; jj < 8; ++jj) o.u[jj] = f2bf(w[c0 + jj]);
    ((int4*)Wp)[(size_t)g * 64 + lane] = o.v;
  } else {                                     // X: 2*144*6 groups
    int gx = g - 216;
    int kc = gx % 6;
    int bnt = gx / 6;                          // b*144 + nt
    int b = bnt / 144;
    int n = (bnt % 144) * 16 + col;
    int c0 = kc * 32 + quad * 8;
    const float* xp = x + ((size_t)b * 192 + c0) * NSP + n;
#pragma unroll
    for (int jj = 0; jj < 8; ++jj) o.u[jj] = f2bf(xp[(size_t)jj * NSP]);
    ((int4*)Xp)[(size_t)gx * 64 + lane] = o.v;
  }
}

// ---------------------------------------------------------------------------
// Kernel 2: MFMA projection GEMM: out[o,n] = sum_c Wall[o,c] x[b,c,n]
//   M=576 (3 weights), K=192 (6 chunks of 32), N=2304. Per wave: 16x64 tile.
//   o<192 -> q (ws), <384 -> k (ws), else v (nt-stored directly to d_out).
//   For q,k rows also accumulates global per-row sum-of-squares (atomics).
// ---------------------------------------------------------------------------
__global__ __launch_bounds__(256) void proj_mfma(
    const bf16x8* __restrict__ Wp, const bf16x8* __restrict__ Xp,
    float* __restrict__ qws, float* __restrict__ kws, float* __restrict__ vout,
    float* __restrict__ sumsq)
{
  int lane = threadIdx.x & 63, w = threadIdx.x >> 6;
  int ng = blockIdx.x * 4 + w;                 // 0..35 (groups of 4 ntiles)
  int mt = blockIdx.y;                         // 0..35
  int b  = blockIdx.z;                         // 0..1
  int nt0 = ng * 4;
  float4v acc0 = {0.f,0.f,0.f,0.f};
  float4v acc1 = acc0, acc2 = acc0, acc3 = acc0;
#pragma unroll
  for (int kc = 0; kc < 6; ++kc) {
    bf16x8 a = Wp[(size_t)(mt * 6 + kc) * 64 + lane];
    const bf16x8* xb = Xp + (size_t)((b * 144 + nt0) * 6 + kc) * 64 + lane;
    acc0 = __builtin_amdgcn_mfma_f32_16x16x32_bf16(a, xb[0],    acc0, 0, 0, 0);
    acc1 = __builtin_amdgcn_mfma_f32_16x16x32_bf16(a, xb[384],  acc1, 0, 0, 0);
    acc2 = __builtin_amdgcn_mfma_f32_16x16x32_bf16(a, xb[768],  acc2, 0, 0, 0);
    acc3 = __builtin_amdgcn_mfma_f32_16x16x32_bf16(a, xb[1152], acc3, 0, 0, 0);
  }
  int quad = lane >> 4, col = lane & 15;
  int o0 = mt * 16 + quad * 4;                 // C/D layout: row = quad*4+reg
  float4v acc[4] = {acc0, acc1, acc2, acc3};
  bool isv = (mt >= 24);
  float* dst;
  if (mt < 12)      dst = qws + ((size_t)b * 192 + o0) * NSP;
  else if (mt < 24) dst = kws + ((size_t)b * 192 + (o0 - 192)) * NSP;
  else              dst = vout + ((size_t)b * 192 + (o0 - 384)) * NSP;
#pragma unroll
  for (int tt = 0; tt < 4; ++tt)
#pragma unroll
    for (int r = 0; r < 4; ++r) {
      float* p = dst + (size_t)r * NSP + (nt0 + tt) * 16 + col;
      if (isv) __builtin_nontemporal_store(acc[tt][r], p);
      else     *p = acc[tt][r];
    }
  if (!isv) {
    // per-row sum of squares over this wave's 64 cols -> atomic accumulate
    float s[4];
#pragma unroll
    for (int r = 0; r < 4; ++r)
      s[r] = acc0[r]*acc0[r] + acc1[r]*acc1[r] + acc2[r]*acc2[r] + acc3[r]*acc3[r];
#pragma unroll
    for (int off = 1; off < 16; off <<= 1)
#pragma unroll
      for (int r = 0; r < 4; ++r) s[r] += __shfl_xor(s[r], off);
    if (col == 0) {
      int base = (mt < 12) ? (b * 192 + mt * 16)
                           : (384 + b * 192 + (mt - 12) * 16);
#pragma unroll
      for (int r = 0; r < 4; ++r)
        atomicAdd(&sumsq[base + quad * 4 + r], s[r]);
    }
  }
}

// ---------------------------------------------------------------------------
// Kernel 3: normalize q,k (inv computed inline from sumsq) and pack into
// attention fragment layout (bf16); temperature folded into K scale.
// One block = 32ch x 64n tile, LDS transpose, 16B coalesced stores.
// ---------------------------------------------------------------------------
__global__ __launch_bounds__(256) void packqk(
    const float* __restrict__ qws, const float* __restrict__ kws,
    const float* __restrict__ sumsq, const float* __restrict__ temp,
    unsigned short* __restrict__ Qp, unsigned short* __restrict__ Kp)
{
  int which = blockIdx.z;                      // 0=q, 1=k
  int bh = blockIdx.y;                         // 0..11
  int nc = blockIdx.x;                         // 0..35 (64-wide n chunks)
  const float* src = which ? kws : qws;
  const float* ssp = sumsq + which * 384;
  int b = bh / 6, h = bh % 6;
  float tmul = which ? temp[h] : 1.0f;         // fold temperature into K
  __shared__ float xs[32][65];
  int t = threadIdx.x;
  const float* base = src + ((size_t)b * 192 + h * 32) * NSP + nc * 64;
#pragma unroll
  for (int i = 0; i < 8; ++i) {
    int idx = t + 256 * i;                     // 2048 = 32x64
    int ch = idx >> 6, nl = idx & 63;
    float ss = ssp[b * 192 + h * 32 + ch];
    float iv = tmul / fmaxf(sqrtf(ss), 1e-12f);
    xs[ch][nl] = base[(size_t)ch * NSP + nl] * iv;
  }
  __syncthreads();
  int jl = t >> 6, lane = t & 63, quad = lane >> 4, col = lane & 15;
  int jt = nc * 4 + jl;
  union { int4 v; unsigned short u[8]; } o;
#pragma unroll
  for (int jj = 0; jj < 8; ++jj) o.u[jj] = f2bf(xs[quad * 8 + jj][jl * 16 + col]);
  int4* dst = (int4*)(which ? Kp : Qp);
  dst[(size_t)(bh * 144 + jt) * 64 + lane] = o.v;
}

// ---------------------------------------------------------------------------
// Kernel 4: attention, SINGLE MFMA+exp pass with LDS staging.
//   Block = one (bh, itile=16 output rows i); 4 waves split the 144 j-tiles.
//   MFMA: A = Q j-tile (m=j), B = K i-tile (n=i) -> D[j][i].
//   Pass 1: exp(S) (T pre-folded into Kp; |S| small -> skip max-subtraction)
//           stored bf16 in LDS [16 i][2312 j-padded]; fp32 row sums.
//   Pass 2: read LDS, scale by 1/rowsum, nontemporal float4 stores (keeps Qp
//           L2-resident instead of thrashing L2 with the 255 MB stream).
// ---------------------------------------------------------------------------
__global__ __launch_bounds__(256) void attn_kernel(
    const bf16x8* __restrict__ Qp, const bf16x8* __restrict__ Kp,
    float* __restrict__ out)
{
  extern __shared__ char smem[];
  unsigned short* eS = (unsigned short*)smem;            // [16][EPAD]
  float* ls   = (float*)(smem + 16 * EPAD * 2);          // [4][16]
  float* invf = ls + 64;                                 // [16]
  int t = threadIdx.x;
  int lane = t & 63, w = t >> 6;
  int itile = blockIdx.x;                      // 0..143
  int bh = blockIdx.y;                         // 0..11
  bf16x8 kf = Kp[((size_t)bh * NT + itile) * 64 + lane]; // B frag: 16 i x 32 ch
  const bf16x8* qb = Qp + (size_t)bh * NT * 64 + lane;
  int quad = lane >> 4, col = lane & 15;
  int jt0 = w * 36;
  float l0 = 0.f, l1 = 0.f, l2 = 0.f, l3 = 0.f;
  unsigned short* ewp = eS + col * EPAD + quad * 4;      // i=col, j base quad*4
  for (int jt = jt0; jt < jt0 + 36; ++jt) {
    bf16x8 qf = qb[(size_t)jt * 64];
    float4v acc = {0.f,0.f,0.f,0.f};
    acc = __builtin_amdgcn_mfma_f32_16x16x32_bf16(qf, kf, acc, 0, 0, 0);
    float e0 = __expf(acc[0]), e1 = __expf(acc[1]);
    float e2 = __expf(acc[2]), e3 = __expf(acc[3]);
    l0 += e0; l1 += e1; l2 += e2; l3 += e3;
    union { uint2 v; unsigned short u[4]; } pk;
    pk.u[0] = f2bf(e0); pk.u[1] = f2bf(e1);
    pk.u[2] = f2bf(e2); pk.u[3] = f2bf(e3);
    *(uint2*)(ewp + jt * 16) = pk.v;
  }
  // lane (quad,col): partial sums over its j for i=col; reduce over quads
  float lsum = (l0 + l1) + (l2 + l3);
  lsum += __shfl_xor(lsum, 16);
  lsum += __shfl_xor(lsum, 32);
  if (lane < 16) ls[w * 16 + lane] = lsum;
  __syncthreads();
  if (t < 16) invf[t] = 1.0f / (ls[t] + ls[16 + t] + ls[32 + t] + ls[48 + t]);
  __syncthreads();
  // Pass 2: 16 rows x 576 float4-chunks = 9216 chunks over 256 threads
  float* obase = out + (size_t)bh * NSP * NSP + (size_t)(itile * 16) * NSP;
#pragma unroll 4
  for (int it = 0; it < 36; ++it) {
    int c = it * 256 + t;
    int i = c / 576;
    int j4 = c - i * 576;
    float iv = invf[i];
    uint2 pk = *(const uint2*)(eS + i * EPAD + j4 * 4);
    float4v o;
    o.x = __uint_as_float(pk.x << 16) * iv;
    o.y = __uint_as_float(pk.x & 0xffff0000u) * iv;
    o.z = __uint_as_float(pk.y << 16) * iv;
    o.w = __uint_as_float(pk.y & 0xffff0000u) * iv;
    __builtin_nontemporal_store(o, (float4v*)(obase + (size_t)i * NSP + j4 * 4));
  }
}

extern "C" void kernel_launch(void* const* d_in, const int* in_sizes, int n_in,
                              void* d_out, int out_size, void* d_ws, size_t ws_size,
                              hipStream_t stream) {
  const float* x    = (const float*)d_in[0];   // [2][192][2304]
  const float* wq   = (const float*)d_in[1];   // [192][192]
  const float* wk   = (const float*)d_in[2];
  const float* wv   = (const float*)d_in[3];
  const float* temp = (const float*)d_in[4];   // [6]

  float* attn_out = (float*)d_out;                     // [2][6][2304][2304]
  float* vout     = attn_out + (size_t)ATTN_ELEMS;     // [2][6][32][2304]

  // workspace carve-up (~12.6 MB total, all 16B-aligned)
  float* qws = (float*)d_ws;                   // 884736 f32
  float* kws = qws + 884736;                   // 884736 f32
  float* sumsq = kws + 884736;                 // 768 f32
  unsigned short* Wp = (unsigned short*)(sumsq + 768); // 110592 bf16
  unsigned short* Xp = Wp + 110592;                    // 884736 bf16
  unsigned short* Qp = Xp + 884736;                    // 884736 bf16
  unsigned short* Kp = Qp + 884736;                    // 884736 bf16

  static bool attr_set = false;
  if (!attr_set) {
    (void)hipFuncSetAttribute((const void*)attn_kernel,
                        hipFuncAttributeMaxDynamicSharedMemorySize, ATTN_LDS);
    attr_set = true;
  }

  hipLaunchKernelGGL(prep_pack, dim3(486), dim3(256), 0, stream,
                     wq, wk, wv, x, Wp, Xp, sumsq);
  hipLaunchKernelGGL(proj_mfma, dim3(9, 36, 2), dim3(256), 0, stream,
                     (const bf16x8*)Wp, (const bf16x8*)Xp, qws, kws, vout, sumsq);
  hipLaunchKernelGGL(packqk, dim3(36, 12, 2), dim3(256), 0, stream,
                     qws, kws, sumsq, temp, Qp, Kp);
  hipLaunchKernelGGL(attn_kernel, dim3(144, 12), dim3(256), ATTN_LDS, stream,
                     (const bf16x8*)Qp, (const bf16x8*)Kp, attn_out);
}